// Round 2
// baseline (266.102 us; speedup 1.0000x reference)
//
#include <hip/hip_runtime.h>

// AtomicComposition: per-structure species histogram.
// Only species (d_in[2]), structure_offsets (d_in[8]), all_species (d_in[9])
// are used. NOTE: structure_offsets is jnp.int64 in source but JAX x64 is
// disabled -> the device buffer is int32 (32768 elements). Casting it to
// int64* caused the R1 memory fault.
//
// Wave-per-structure: atoms of structure s occupy [offsets[s], offsets[s+1])
// contiguously, so one 64-lane wave counts its 256 atoms with int4 loads +
// register compares, reduces via shfl_xor on a packed u64 (5 bins x 12 bits),
// and writes 5 floats. No atomics, no global zeroing required (every output
// bin is written unconditionally).

__global__ __launch_bounds__(256) void atomic_composition_kernel(
    const int* __restrict__ species,
    const int* __restrict__ offsets,     // int32! (see note above)
    const int* __restrict__ all_species,
    float* __restrict__ out,
    int n_structures,
    int n_atoms)
{
    const int wid  = (int)((blockIdx.x * 256u + threadIdx.x) >> 6);
    const int lane = (int)(threadIdx.x & 63u);
    if (wid >= n_structures) return;

    // 5 species values -> registers (same address per wave: broadcast)
    const int s0 = all_species[0];
    const int s1 = all_species[1];
    const int s2 = all_species[2];
    const int s3 = all_species[3];
    const int s4 = all_species[4];

    const int start = offsets[wid];
    const int end   = (wid + 1 < n_structures) ? offsets[wid + 1] : n_atoms;

    // Packed per-lane histogram: bin k occupies bits [12k, 12k+12)
    unsigned long long local = 0ull;

    const int cnt = end - start;
    if (cnt == 256 && ((start & 3) == 0)) {
        // Fast path: exactly 256 atoms, 16B-aligned — one int4 per lane.
        const int4* p = reinterpret_cast<const int4*>(species + start);
        int4 v = p[lane];
        int zs[4] = { v.x, v.y, v.z, v.w };
#pragma unroll
        for (int j = 0; j < 4; ++j) {
            int z = zs[j];
            z = min(max(z, 0), 127);   // reference clips to [0, MAX_Z-1]
            if      (z == s0) local += 1ull;
            else if (z == s1) local += (1ull << 12);
            else if (z == s2) local += (1ull << 24);
            else if (z == s3) local += (1ull << 36);
            else if (z == s4) local += (1ull << 48);
        }
    } else {
        // Generic path: arbitrary atom count per structure.
        for (int i = start + lane; i < end; i += 64) {
            int z = species[i];
            z = min(max(z, 0), 127);
            if      (z == s0) local += 1ull;
            else if (z == s1) local += (1ull << 12);
            else if (z == s2) local += (1ull << 24);
            else if (z == s3) local += (1ull << 36);
            else if (z == s4) local += (1ull << 48);
        }
    }

    // Wave-wide sum of the packed u64 (fields can't overflow: <=4096/bin)
#pragma unroll
    for (int off = 32; off > 0; off >>= 1)
        local += __shfl_xor(local, off, 64);

    if (lane < 5) {
        out[wid * 5 + lane] =
            (float)((local >> (12 * lane)) & 0xFFFull);
    }
}

extern "C" void kernel_launch(void* const* d_in, const int* in_sizes, int n_in,
                              void* d_out, int out_size, void* d_ws, size_t ws_size,
                              hipStream_t stream) {
    const int* species     = (const int*)d_in[2];
    const int* offsets     = (const int*)d_in[8];
    const int* all_species = (const int*)d_in[9];
    float*     out         = (float*)d_out;

    const int n_structures = in_sizes[8];   // 32768
    const int n_atoms      = in_sizes[2];   // 8388608

    // one wave (64 lanes) per structure, 4 waves per 256-thread block
    const int blocks = (n_structures + 3) / 4;
    atomic_composition_kernel<<<blocks, 256, 0, stream>>>(
        species, offsets, all_species, out, n_structures, n_atoms);
}

// Round 4
// 264.246 us; speedup vs baseline: 1.0070x; 1.0070x over previous
//
#include <hip/hip_runtime.h>

// AtomicComposition: per-structure species histogram.
// Only species (d_in[2]), structure_offsets (d_in[8], int32 on device —
// JAX x64 disabled), all_species (d_in[9]) are used.
//
// Wave-per-structure: atoms of structure s occupy [offsets[s], offsets[s+1])
// contiguously; one 64-lane wave counts its 256 atoms with one int4
// nontemporal load per lane (species is read-once: bypass L2), reduces via
// shfl_xor on a packed u64 (5 bins x 12 bits), and writes 5 floats.
// No atomics, no global zeroing (every output bin written unconditionally).
//
// R2 counters: kernel absent from top-5 (<58us); dur_us=266 dominated by
// harness re-poison fills (404MB @ 59us each). R3: nontemporal builtin needs
// a native clang vector type, not HIP_vector_type -> ext_vector_type(4).

typedef int vint4 __attribute__((ext_vector_type(4)));

__global__ __launch_bounds__(256) void atomic_composition_kernel(
    const int* __restrict__ species,
    const int* __restrict__ offsets,     // int32 (see note above)
    const int* __restrict__ all_species,
    float* __restrict__ out,
    int n_structures,
    int n_atoms)
{
    const int wid  = (int)((blockIdx.x * 256u + threadIdx.x) >> 6);
    const int lane = (int)(threadIdx.x & 63u);
    if (wid >= n_structures) return;

    // Issue the bounds loads immediately (wave-uniform -> scalar/broadcast).
    const int start = offsets[wid];
    const int end   = (wid + 1 < n_structures) ? offsets[wid + 1] : n_atoms;

    // 5 species values -> registers (wave-uniform broadcast)
    const int s0 = all_species[0];
    const int s1 = all_species[1];
    const int s2 = all_species[2];
    const int s3 = all_species[3];
    const int s4 = all_species[4];

    // Packed per-lane histogram: bin k occupies bits [12k, 12k+12)
    unsigned long long local = 0ull;

    const int cnt = end - start;
    if (cnt == 256 && ((start & 3) == 0)) {
        // Fast path: exactly 256 atoms, 16B-aligned — one 16B load per lane,
        // nontemporal (read-once stream, don't pollute L2).
        const vint4* p = reinterpret_cast<const vint4*>(species + start);
        vint4 v = __builtin_nontemporal_load(&p[lane]);
#pragma unroll
        for (int j = 0; j < 4; ++j) {
            int z = v[j];
            z = min(max(z, 0), 127);   // reference clips to [0, MAX_Z-1]
            if      (z == s0) local += 1ull;
            else if (z == s1) local += (1ull << 12);
            else if (z == s2) local += (1ull << 24);
            else if (z == s3) local += (1ull << 36);
            else if (z == s4) local += (1ull << 48);
        }
    } else {
        // Generic path: arbitrary atom count per structure.
        for (int i = start + lane; i < end; i += 64) {
            int z = species[i];
            z = min(max(z, 0), 127);
            if      (z == s0) local += 1ull;
            else if (z == s1) local += (1ull << 12);
            else if (z == s2) local += (1ull << 24);
            else if (z == s3) local += (1ull << 36);
            else if (z == s4) local += (1ull << 48);
        }
    }

    // Wave-wide sum of the packed u64 (fields can't overflow: <=4096/bin)
#pragma unroll
    for (int off = 32; off > 0; off >>= 1)
        local += __shfl_xor(local, off, 64);

    if (lane < 5) {
        out[wid * 5 + lane] =
            (float)((local >> (12 * lane)) & 0xFFFull);
    }
}

extern "C" void kernel_launch(void* const* d_in, const int* in_sizes, int n_in,
                              void* d_out, int out_size, void* d_ws, size_t ws_size,
                              hipStream_t stream) {
    const int* species     = (const int*)d_in[2];
    const int* offsets     = (const int*)d_in[8];
    const int* all_species = (const int*)d_in[9];
    float*     out         = (float*)d_out;

    const int n_structures = in_sizes[8];   // 32768
    const int n_atoms      = in_sizes[2];   // 8388608

    // one wave (64 lanes) per structure, 4 waves per 256-thread block
    const int blocks = (n_structures + 3) / 4;
    atomic_composition_kernel<<<blocks, 256, 0, stream>>>(
        species, offsets, all_species, out, n_structures, n_atoms);
}